// Round 5
// baseline (103.164 us; speedup 1.0000x reference)
//
#include <hip/hip_runtime.h>
#include <hip/hip_bf16.h>

#define SPATIAL_SCALE 0.125f
#define POOLED 7
#define PART 7
#define SAMPLES 4
#define TRANS_STD 0.1f

#define B_DIM 4
#define C_DIM 256
#define H_DIM 64
#define W_DIM 64
#define BINS (POOLED * POOLED)   // 49

// ---------------------------------------------------------------------------
// NCHW -> NHWC transpose: data[b][c][y][x] -> data_t[b][y][x][c]
// ---------------------------------------------------------------------------
#define TS 32
__global__ __launch_bounds__(256) void nchw_to_nhwc(const float* __restrict__ in,
                                                    float* __restrict__ out) {
    __shared__ float tile[TS][TS + 1];
    const int b   = blockIdx.z;
    const int hw0 = blockIdx.x * TS;
    const int c0  = blockIdx.y * TS;
    const int tx  = threadIdx.x;
    const int ty  = threadIdx.y;

    const float* inb  = in  + (size_t)b * C_DIM * (H_DIM * W_DIM);
    float*       outb = out + (size_t)b * (H_DIM * W_DIM) * C_DIM;

    #pragma unroll
    for (int i = ty; i < TS; i += 8)
        tile[i][tx] = inb[(size_t)(c0 + i) * (H_DIM * W_DIM) + (hw0 + tx)];
    __syncthreads();
    #pragma unroll
    for (int i = ty; i < TS; i += 8)
        outb[(size_t)(hw0 + i) * C_DIM + (c0 + tx)] = tile[tx][i];
}

// ---------------------------------------------------------------------------
// Fused pool + output layout. One block per ROI (grid = N), 512 threads =
// 8 waves; wave w handles bins w, w+8, ... (49 bins). Lane covers channels
// {lane, lane+64, lane+128, lane+192} so:
//   - global loads per footprint pixel: 4 x dword, lane-contiguous 256 B each
//     (same 16 L1 lines/pixel as one float4 load),
//   - LDS stores go to addr c*49+bin, stride 49 (odd) per c-step ->
//     conflict-free (2 lanes/bank = free per m136).
// LDS layout [c][bin] flat == out[n] layout [c][ph][pw] flat, so writeback is
// the identity: a fully-coalesced, amplification-free 50 KB contiguous store.
// This removes round-4's tmp buffer (25.6 MB round-trip), the layout kernel,
// and one dispatch gap. Separable weight aggregation identical to round-4
// pool (bit-identical geometry math; only /cnt -> *(1/cnt)).
// ---------------------------------------------------------------------------
__global__ __launch_bounds__(512) void pool_fused(const float* __restrict__ src,   // NHWC
                                                  const float* __restrict__ rois,
                                                  const float* __restrict__ offset,
                                                  float* __restrict__ out,
                                                  int N) {
    __shared__ float lds[C_DIM * BINS];   // 12544 floats = 49 KB
    const int n    = blockIdx.x;
    const int t    = threadIdx.x;
    const int wave = t >> 6;      // 0..7
    const int lane = t & 63;

    const float* roi = rois + (size_t)n * 5;
    const int b = (int)roi[0];

    // ROI-uniform geometry (identical expressions to rounds 2-4, which passed)
    const float roi_sw = rintf(roi[1]) * SPATIAL_SCALE - 0.5f;
    const float roi_sh = rintf(roi[2]) * SPATIAL_SCALE - 0.5f;
    const float roi_ew = (rintf(roi[3]) + 1.0f) * SPATIAL_SCALE - 0.5f;
    const float roi_eh = (rintf(roi[4]) + 1.0f) * SPATIAL_SCALE - 0.5f;
    const float roi_w = fmaxf(roi_ew - roi_sw, 0.1f);
    const float roi_h = fmaxf(roi_eh - roi_sh, 0.1f);
    const float bin_w = roi_w / (float)POOLED;
    const float bin_h = roi_h / (float)POOLED;
    const float sub_w = bin_w / (float)SAMPLES;
    const float sub_h = bin_h / (float)SAMPLES;

    const float* baseb = src + (size_t)b * (H_DIM * W_DIM) * C_DIM;

    for (int bin = wave; bin < BINS; bin += 8) {
        const int ph = bin / POOLED;
        const int pw = bin - ph * POOLED;

        int part_h = (int)floorf(((float)ph / (float)POOLED) * (float)PART);
        int part_w = (int)floorf(((float)pw / (float)POOLED) * (float)PART);
        part_h = min(max(part_h, 0), PART - 1);
        part_w = min(max(part_w, 0), PART - 1);

        const float tx = offset[(((size_t)n * 2 + 0) * PART + part_h) * PART + part_w] * TRANS_STD;
        const float ty = offset[(((size_t)n * 2 + 1) * PART + part_h) * PART + part_w] * TRANS_STD;

        const float wstart = (float)pw * bin_w + roi_sw + tx * roi_w;
        const float hstart = (float)ph * bin_h + roi_sh + ty * roi_h;

        // per-axis aggregated weights (w strictly increasing in sw -> first
        // valid sample's x0 is the footprint minimum; footprint <= 4 cells)
        float Wx[4] = {0.f, 0.f, 0.f, 0.f};
        int xmin = 0, nvw = 0;
        #pragma unroll
        for (int sw = 0; sw < SAMPLES; ++sw) {
            const float w = wstart + (float)sw * sub_w;
            if (w > -0.5f && w < (float)W_DIM - 0.5f) {
                const float wc = fminf(fmaxf(w, 0.0f), (float)(W_DIM - 1));
                const int x0 = (int)floorf(wc);
                const int x1 = min(x0 + 1, W_DIM - 1);
                const float dx = wc - (float)x0;
                if (nvw == 0) xmin = x0;
                ++nvw;
                const int i0 = x0 - xmin;
                const int i1 = x1 - xmin;
                const float w0 = 1.0f - dx;
                Wx[0] += (i0 == 0 ? w0 : 0.f) + (i1 == 0 ? dx : 0.f);
                Wx[1] += (i0 == 1 ? w0 : 0.f) + (i1 == 1 ? dx : 0.f);
                Wx[2] += (i0 == 2 ? w0 : 0.f) + (i1 == 2 ? dx : 0.f);
                Wx[3] += (i1 == 3 ? dx : 0.f);
            }
        }

        float Wy[4] = {0.f, 0.f, 0.f, 0.f};
        int ymin = 0, nvh = 0;
        #pragma unroll
        for (int sh = 0; sh < SAMPLES; ++sh) {
            const float h = hstart + (float)sh * sub_h;
            if (h > -0.5f && h < (float)H_DIM - 0.5f) {
                const float hc = fminf(fmaxf(h, 0.0f), (float)(H_DIM - 1));
                const int y0 = (int)floorf(hc);
                const int y1 = min(y0 + 1, H_DIM - 1);
                const float dy = hc - (float)y0;
                if (nvh == 0) ymin = y0;
                ++nvh;
                const int i0 = y0 - ymin;
                const int i1 = y1 - ymin;
                const float w0 = 1.0f - dy;
                Wy[0] += (i0 == 0 ? w0 : 0.f) + (i1 == 0 ? dy : 0.f);
                Wy[1] += (i0 == 1 ? w0 : 0.f) + (i1 == 1 ? dy : 0.f);
                Wy[2] += (i0 == 2 ? w0 : 0.f) + (i1 == 2 ? dy : 0.f);
                Wy[3] += (i1 == 3 ? dy : 0.f);
            }
        }

        const int cnt = nvw * nvh;
        float a0 = 0.f, a1 = 0.f, a2 = 0.f, a3 = 0.f;

        if (cnt > 0) {
            #pragma unroll
            for (int iy = 0; iy < 4; ++iy) {
                if (Wy[iy] == 0.f) continue;           // wave-uniform, exact
                const int rowoff = (ymin + iy) * W_DIM + xmin;
                #pragma unroll
                for (int ix = 0; ix < 4; ++ix) {
                    if (Wx[ix] == 0.f) continue;       // wave-uniform, exact
                    const float wgt = Wy[iy] * Wx[ix];
                    const float* p = baseb + (size_t)(rowoff + ix) * C_DIM + lane;
                    a0 = fmaf(wgt, p[0],   a0);
                    a1 = fmaf(wgt, p[64],  a1);
                    a2 = fmaf(wgt, p[128], a2);
                    a3 = fmaf(wgt, p[192], a3);
                }
            }
            const float rinv = 1.0f / (float)cnt;
            a0 *= rinv; a1 *= rinv; a2 *= rinv; a3 *= rinv;
        }

        lds[(lane       ) * BINS + bin] = a0;
        lds[(lane +  64 ) * BINS + bin] = a1;
        lds[(lane + 128 ) * BINS + bin] = a2;
        lds[(lane + 192 ) * BINS + bin] = a3;
    }

    __syncthreads();

    // identity writeback: lds [c][bin] flat == out[n] [c][ph][pw] flat
    float* on = out + (size_t)n * (C_DIM * BINS);
    for (int j = t; j < C_DIM * BINS; j += 512)
        on[j] = lds[j];
}

// ---------------------------------------------------------------------------
// Fallback: direct NCHW gather (only if workspace too small for staging).
// ---------------------------------------------------------------------------
__global__ __launch_bounds__(256) void deform_roi_pool_nchw(const float* __restrict__ src,
                                                            const float* __restrict__ rois,
                                                            const float* __restrict__ offset,
                                                            float* __restrict__ out,
                                                            int N) {
    const int blk = blockIdx.x;
    const int n   = blk / BINS;
    const int bin = blk % BINS;
    const int ph  = bin / POOLED;
    const int pw  = bin % POOLED;
    const int c   = threadIdx.x;
    if (n >= N) return;

    const float* roi = rois + (size_t)n * 5;
    const int b = (int)roi[0];

    const float roi_sw = rintf(roi[1]) * SPATIAL_SCALE - 0.5f;
    const float roi_sh = rintf(roi[2]) * SPATIAL_SCALE - 0.5f;
    const float roi_ew = (rintf(roi[3]) + 1.0f) * SPATIAL_SCALE - 0.5f;
    const float roi_eh = (rintf(roi[4]) + 1.0f) * SPATIAL_SCALE - 0.5f;
    const float roi_w = fmaxf(roi_ew - roi_sw, 0.1f);
    const float roi_h = fmaxf(roi_eh - roi_sh, 0.1f);
    const float bin_w = roi_w / (float)POOLED;
    const float bin_h = roi_h / (float)POOLED;
    const float sub_w = bin_w / (float)SAMPLES;
    const float sub_h = bin_h / (float)SAMPLES;

    int part_h = (int)floorf(((float)ph / (float)POOLED) * (float)PART);
    int part_w = (int)floorf(((float)pw / (float)POOLED) * (float)PART);
    part_h = min(max(part_h, 0), PART - 1);
    part_w = min(max(part_w, 0), PART - 1);

    const float tx = offset[(((size_t)n * 2 + 0) * PART + part_h) * PART + part_w] * TRANS_STD;
    const float ty = offset[(((size_t)n * 2 + 1) * PART + part_h) * PART + part_w] * TRANS_STD;

    const float wstart = (float)pw * bin_w + roi_sw + tx * roi_w;
    const float hstart = (float)ph * bin_h + roi_sh + ty * roi_h;

    float sum = 0.0f;
    int cnt = 0;

    #pragma unroll
    for (int sh = 0; sh < SAMPLES; ++sh) {
        const float h = hstart + (float)sh * sub_h;
        #pragma unroll
        for (int sw = 0; sw < SAMPLES; ++sw) {
            const float w = wstart + (float)sw * sub_w;
            const bool valid = (w > -0.5f) && (w < (float)W_DIM - 0.5f) &&
                               (h > -0.5f) && (h < (float)H_DIM - 0.5f);
            if (!valid) continue;
            ++cnt;
            const float wc = fminf(fmaxf(w, 0.0f), (float)(W_DIM - 1));
            const float hc = fminf(fmaxf(h, 0.0f), (float)(H_DIM - 1));
            const int x0 = (int)floorf(wc);
            const int y0 = (int)floorf(hc);
            const int x1 = min(x0 + 1, W_DIM - 1);
            const int y1 = min(y0 + 1, H_DIM - 1);
            const float dx = wc - (float)x0;
            const float dy = hc - (float)y0;

            const size_t base = ((size_t)b * C_DIM + c) * (H_DIM * W_DIM);
            const float v00 = src[base + (size_t)y0 * W_DIM + x0];
            const float v01 = src[base + (size_t)y0 * W_DIM + x1];
            const float v10 = src[base + (size_t)y1 * W_DIM + x0];
            const float v11 = src[base + (size_t)y1 * W_DIM + x1];
            sum += (1.0f - dx) * (1.0f - dy) * v00
                 + (1.0f - dx) * dy          * v10
                 + dx          * (1.0f - dy) * v01
                 + dx          * dy          * v11;
        }
    }

    const float res = (cnt > 0) ? sum / (float)cnt : 0.0f;
    out[(((size_t)n * C_DIM + c) * POOLED + ph) * POOLED + pw] = res;
}

extern "C" void kernel_launch(void* const* d_in, const int* in_sizes, int n_in,
                              void* d_out, int out_size, void* d_ws, size_t ws_size,
                              hipStream_t stream) {
    const float* data   = (const float*)d_in[0];
    const float* rois   = (const float*)d_in[1];
    const float* offset = (const float*)d_in[2];
    float* out = (float*)d_out;
    const int N = in_sizes[1] / 5;

    const size_t nhwc_bytes = (size_t)B_DIM * C_DIM * H_DIM * W_DIM * sizeof(float);

    if (ws_size >= nhwc_bytes) {
        float* data_t = (float*)d_ws;
        dim3 tb(32, 8, 1);
        dim3 tg((H_DIM * W_DIM) / TS, C_DIM / TS, B_DIM);
        nchw_to_nhwc<<<tg, tb, 0, stream>>>(data, data_t);
        pool_fused<<<N, 512, 0, stream>>>(data_t, rois, offset, out, N);
    } else {
        deform_roi_pool_nchw<<<N * BINS, C_DIM, 0, stream>>>(
            data, rois, offset, out, N);
    }
}